// Round 7
// baseline (730.996 us; speedup 1.0000x reference)
//
#include <hip/hip_runtime.h>
#include <cstdint>
#include <cstddef>

#define NEG_SLOPE 0.2f

typedef __bf16 bf16x8 __attribute__((ext_vector_type(8)));
typedef __bf16 bf16x4 __attribute__((ext_vector_type(4)));
typedef float f32x4 __attribute__((ext_vector_type(4)));

// ---------- merged independent prep: prep_v1 | prep_v2 | W1 transpose | deg ----------
// block ranges: [0] v1, [1,2] v2, [3,130] transpose, [131,131+degBlocks) deg
__global__ __launch_bounds__(256) void prep_all_kernel(
    const float* __restrict__ W1, const float* __restrict__ as1, const float* __restrict__ ad1,
    const float* __restrict__ W2, const float* __restrict__ as2, const float* __restrict__ ad2,
    const int* __restrict__ ei, int E,
    float* __restrict__ Vs, float* __restrict__ Vd,
    float* __restrict__ vs2, float* __restrict__ vd2,
    __bf16* __restrict__ W1T, int* __restrict__ deg) {
  int bid = blockIdx.x, tid = threadIdx.x;
  if (bid == 0) {
    // Vs1[k,h] = sum_c W1[k, h*128+c] * a1[h,c]  (64x4)
    int k = tid >> 2, h = tid & 3;
    const float* w = W1 + k * 512 + h * 128;
    const float* a1 = as1 + h * 128;
    const float* a2 = ad1 + h * 128;
    float s = 0.f, d = 0.f;
    for (int c = 0; c < 128; ++c) { float wv = w[c]; s += wv * a1[c]; d += wv * a2[c]; }
    Vs[k * 4 + h] = s; Vd[k * 4 + h] = d;
  } else if (bid <= 2) {
    int k = (bid - 1) * 256 + tid;
    if (k < 512) {
      const float* w = W2 + k * 256;
      float s = 0.f, d = 0.f;
      for (int c = 0; c < 256; ++c) { float wv = w[c]; s += wv * as2[c]; d += wv * ad2[c]; }
      vs2[k] = s; vd2[k] = d;
    }
  } else if (bid <= 130) {
    int idx = (bid - 3) * 256 + tid;   // < 32768
    int n = idx >> 6, k = idx & 63;    // W1T[n*64+k] = W1[k*512+n]
    W1T[idx] = (__bf16)W1[(size_t)k * 512 + n];
  } else {
    int t = (bid - 131) * 256 + tid;
    int base = t * 4;
    if (base >= E) return;
    if (base + 4 <= E) {
      int4 d4 = *(const int4*)(ei + E + base);
      atomicAdd(&deg[d4.x], 1);
      atomicAdd(&deg[d4.y], 1);
      atomicAdd(&deg[d4.z], 1);
      atomicAdd(&deg[d4.w], 1);
    } else {
      for (int e = base; e < E; ++e) atomicAdd(&deg[ei[E + e]], 1);
    }
  }
}

// ---------- fused emb -> bf16 + alpha1 ----------
__global__ void emb_prep_kernel(const float* __restrict__ emb, const float* __restrict__ Vs,
                                const float* __restrict__ Vd, __bf16* __restrict__ embb,
                                float* __restrict__ as_, float* __restrict__ ad_, int n) {
  __shared__ float sVs[256];
  __shared__ float sVd[256];
  for (int i = threadIdx.x; i < 256; i += blockDim.x) { sVs[i] = Vs[i]; sVd[i] = Vd[i]; }
  __syncthreads();
  int node = blockIdx.x * blockDim.x + threadIdx.x;
  if (node >= n) return;
  const float* xr = emb + (size_t)node * 64;
  __bf16* br = embb + (size_t)node * 64;
  float accs[4] = {}, accd[4] = {};
  for (int k = 0; k < 64; k += 4) {
    float4 xv = *(const float4*)(xr + k);
    bf16x4 o;
    o[0] = (__bf16)xv.x; o[1] = (__bf16)xv.y; o[2] = (__bf16)xv.z; o[3] = (__bf16)xv.w;
    *(bf16x4*)(br + k) = o;
#pragma unroll
    for (int h = 0; h < 4; ++h) {
      accs[h] += xv.x * sVs[(k + 0) * 4 + h] + xv.y * sVs[(k + 1) * 4 + h] +
                 xv.z * sVs[(k + 2) * 4 + h] + xv.w * sVs[(k + 3) * 4 + h];
      accd[h] += xv.x * sVd[(k + 0) * 4 + h] + xv.y * sVd[(k + 1) * 4 + h] +
                 xv.z * sVd[(k + 2) * 4 + h] + xv.w * sVd[(k + 3) * 4 + h];
    }
  }
#pragma unroll
  for (int h = 0; h < 4; ++h) {
    as_[(size_t)node * 4 + h] = accs[h];
    ad_[(size_t)node * 4 + h] = accd[h];
  }
}

// ---------- CSR scan ----------
__global__ void scan_reduce_kernel(const int* __restrict__ deg, int* __restrict__ partial, int n) {
  __shared__ int ws[4];
  int i = blockIdx.x * 256 + threadIdx.x;
  int v = (i < n) ? deg[i] + 1 : 0;
  int lane = threadIdx.x & 63, w = threadIdx.x >> 6;
#pragma unroll
  for (int s = 32; s; s >>= 1) v += __shfl_down(v, s, 64);
  if (lane == 0) ws[w] = v;
  __syncthreads();
  if (threadIdx.x == 0) partial[blockIdx.x] = ws[0] + ws[1] + ws[2] + ws[3];
}

// scan_final with inline prefix over partials (each block sums partial[k<b] itself)
__global__ void scan_final_kernel(const int* __restrict__ deg, const int* __restrict__ partial,
                                  int* __restrict__ off, int n) {
  __shared__ int ws[4];
  __shared__ int bsum[4];
  __shared__ int sbase;
  int b = blockIdx.x, t = threadIdx.x;
  int lane = t & 63, w = t >> 6;
  // base = sum partial[0..b-1]
  int ps = (t < b) ? partial[t] : 0;    // b <= 255 assumed (n <= 65536)
#pragma unroll
  for (int s = 32; s; s >>= 1) ps += __shfl_down(ps, s, 64);
  if (lane == 0) bsum[w] = ps;
  __syncthreads();
  if (t == 0) sbase = bsum[0] + bsum[1] + bsum[2] + bsum[3];
  int i = b * 256 + t;
  int v = (i < n) ? deg[i] + 1 : 0;
  int x = v;
#pragma unroll
  for (int s = 1; s < 64; s <<= 1) {
    int tt = __shfl_up(x, s, 64);
    if (lane >= s) x += tt;
  }
  if (lane == 63) ws[w] = x;
  __syncthreads();
  int wo = 0;
  for (int k = 0; k < w; ++k) wo += ws[k];
  int base = sbase;
  if (i < n) off[i] = base + wo + x - v;
  if (i == n - 1) off[n] = base + wo + x;
}

// ---------- scatter real edges + self-loop tail slot ----------
__global__ void scatter_kernel(const int* __restrict__ ei, int E, const int* __restrict__ off,
                               int* __restrict__ cursor, int* __restrict__ csr_src, int n,
                               int scatterBlocks) {
  if ((int)blockIdx.x < scatterBlocks) {
    int e = blockIdx.x * 256 + threadIdx.x;
    if (e >= E) return;
    int s = ei[e], d = ei[E + e];
    int p = atomicAdd(&cursor[d], 1);
    csr_src[off[d] + p] = s;
  } else {
    int d = (blockIdx.x - scatterBlocks) * 256 + threadIdx.x;
    if (d < n) csr_src[off[d + 1] - 1] = d;
  }
}

// ---------- layer-1 aggregation in EMBEDDING space, 4 edges in flight ----------
__global__ __launch_bounds__(128) void agg_emb_kernel(
    const int* __restrict__ off, const int* __restrict__ csr_src,
    const __bf16* __restrict__ embb, const float* __restrict__ as_,
    const float* __restrict__ ad_, __bf16* __restrict__ aggE) {
  int d = blockIdx.x * 2 + (threadIdx.x >> 6);
  int lane = threadIdx.x & 63;
  int g = lane >> 4, p = lane & 15;
  float4 adv = *(const float4*)(ad_ + (size_t)d * 4);
  float acc[4][4] = {};   // [head][chan]
  float wsum[4] = {};
  int beg = off[d], end = off[d + 1];
  for (int i0 = beg; i0 < end; i0 += 4) {
    int i = i0 + g;
    float vm = (i < end) ? 1.f : 0.f;
    int idx = (i < end) ? i : (end - 1);
    int s = csr_src[idx];
    float4 asv = *(const float4*)(as_ + (size_t)s * 4);
    float l0 = asv.x + adv.x; l0 = l0 >= 0.f ? l0 : NEG_SLOPE * l0;
    float l1 = asv.y + adv.y; l1 = l1 >= 0.f ? l1 : NEG_SLOPE * l1;
    float l2 = asv.z + adv.z; l2 = l2 >= 0.f ? l2 : NEG_SLOPE * l2;
    float l3 = asv.w + adv.w; l3 = l3 >= 0.f ? l3 : NEG_SLOPE * l3;
    float w0 = __expf(l0) * vm, w1 = __expf(l1) * vm;
    float w2 = __expf(l2) * vm, w3 = __expf(l3) * vm;
    bf16x4 v = *(const bf16x4*)(embb + (size_t)s * 64 + p * 4);
    float f0 = (float)v[0], f1 = (float)v[1], f2 = (float)v[2], f3 = (float)v[3];
    acc[0][0] += w0 * f0; acc[0][1] += w0 * f1; acc[0][2] += w0 * f2; acc[0][3] += w0 * f3;
    acc[1][0] += w1 * f0; acc[1][1] += w1 * f1; acc[1][2] += w1 * f2; acc[1][3] += w1 * f3;
    acc[2][0] += w2 * f0; acc[2][1] += w2 * f1; acc[2][2] += w2 * f2; acc[2][3] += w2 * f3;
    acc[3][0] += w3 * f0; acc[3][1] += w3 * f1; acc[3][2] += w3 * f2; acc[3][3] += w3 * f3;
    wsum[0] += w0; wsum[1] += w1; wsum[2] += w2; wsum[3] += w3;
  }
#pragma unroll
  for (int h = 0; h < 4; ++h) {
#pragma unroll
    for (int c = 0; c < 4; ++c) {
      acc[h][c] += __shfl_xor(acc[h][c], 16, 64);
      acc[h][c] += __shfl_xor(acc[h][c], 32, 64);
    }
    wsum[h] += __shfl_xor(wsum[h], 16, 64);
    wsum[h] += __shfl_xor(wsum[h], 32, 64);
  }
  if (g == 0) {
#pragma unroll
    for (int h = 0; h < 4; ++h) {
      float inv = 1.0f / wsum[h];
      bf16x4 o;
      o[0] = (__bf16)(acc[h][0] * inv); o[1] = (__bf16)(acc[h][1] * inv);
      o[2] = (__bf16)(acc[h][2] * inv); o[3] = (__bf16)(acc[h][3] * inv);
      *(bf16x4*)(aggE + (size_t)d * 256 + h * 64 + p * 4) = o;
    }
  }
}

// ---------- reconstruct x1 (per-head MFMA GEMM + bias + ELU) with fused alpha2 partials ----------
__global__ __launch_bounds__(256) void gemm1p_kernel(const __bf16* __restrict__ aggE,
                                                     const __bf16* __restrict__ W1T,
                                                     const float* __restrict__ b1,
                                                     const float* __restrict__ vs2,
                                                     const float* __restrict__ vd2,
                                                     __bf16* __restrict__ x1,
                                                     float* __restrict__ as2p,
                                                     float* __restrict__ ad2p, int M) {
  __shared__ __bf16 Asl[128 * 72];
  __shared__ __bf16 Bsl[128 * 72];
  int tid = threadIdx.x;
  int h = blockIdx.z;
  int m0 = blockIdx.x * 128;
  int wave = tid >> 6, lane = tid & 63;
  int wm = (wave >> 1) * 64, wn = (wave & 1) * 64;
  int l15 = lane & 15, kg = lane >> 4;
#pragma unroll
  for (int i = 0; i < 4; ++i) {
    int c = tid + i * 256;
    int row = c >> 3, off = (c & 7) * 8;
    bf16x8 va = {};
    int gr = m0 + row;
    if (gr < M) va = *(const bf16x8*)(aggE + (size_t)gr * 256 + h * 64 + off);
    *(bf16x8*)(&Asl[row * 72 + off]) = va;
    bf16x8 vb = *(const bf16x8*)(W1T + ((size_t)h * 128 + row) * 64 + off);
    *(bf16x8*)(&Bsl[row * 72 + off]) = vb;
  }
  __syncthreads();
  f32x4 acc[4][4] = {};
#pragma unroll
  for (int ks = 0; ks < 2; ++ks) {
    bf16x8 af[4], bfr[4];
#pragma unroll
    for (int f = 0; f < 4; ++f) {
      af[f]  = *(const bf16x8*)(&Asl[(wm + f * 16 + l15) * 72 + kg * 8 + ks * 32]);
      bfr[f] = *(const bf16x8*)(&Bsl[(wn + f * 16 + l15) * 72 + kg * 8 + ks * 32]);
    }
#pragma unroll
    for (int i = 0; i < 4; ++i)
#pragma unroll
      for (int j = 0; j < 4; ++j)
        acc[i][j] = __builtin_amdgcn_mfma_f32_16x16x32_bf16(af[i], bfr[j], acc[i][j], 0, 0, 0);
  }
  float bv[4], vsv[4], vdv[4];
#pragma unroll
  for (int j = 0; j < 4; ++j) {
    int col = h * 128 + wn + j * 16 + l15;
    bv[j] = b1[col]; vsv[j] = vs2[col]; vdv[j] = vd2[col];
  }
  int slab = h * 2 + (wn >> 6);
#pragma unroll
  for (int i = 0; i < 4; ++i)
#pragma unroll
    for (int r = 0; r < 4; ++r) {
      int lrow = wm + i * 16 + kg * 4 + r;
      int row = m0 + lrow;
      bool vrow = row < M;
      float ps = 0.f, pd = 0.f;
#pragma unroll
      for (int j = 0; j < 4; ++j) {
        float a = acc[i][j][r] + bv[j];
        a = a > 0.f ? a : __expf(a) - 1.f;   // ELU
        __bf16 xb = (__bf16)a;
        if (vrow) x1[(size_t)row * 512 + h * 128 + wn + j * 16 + l15] = xb;
        float af = (float)xb;
        ps += af * vsv[j];
        pd += af * vdv[j];
      }
      ps += __shfl_xor(ps, 1, 16); ps += __shfl_xor(ps, 2, 16);
      ps += __shfl_xor(ps, 4, 16); ps += __shfl_xor(ps, 8, 16);
      pd += __shfl_xor(pd, 1, 16); pd += __shfl_xor(pd, 2, 16);
      pd += __shfl_xor(pd, 4, 16); pd += __shfl_xor(pd, 8, 16);
      if (l15 == 0 && vrow) {
        as2p[(size_t)slab * M + row] = ps;
        ad2p[(size_t)slab * M + row] = pd;
      }
    }
}

// ---------- merge alpha2 partial slabs ----------
__global__ void merge_alpha2_kernel(const float* __restrict__ as2p, const float* __restrict__ ad2p,
                                    float* __restrict__ as2, float* __restrict__ ad2, int n) {
  int i = blockIdx.x * blockDim.x + threadIdx.x;
  if (i >= n) return;
  float s = 0.f, d = 0.f;
#pragma unroll
  for (int b = 0; b < 8; ++b) {
    s += as2p[(size_t)b * n + i];
    d += ad2p[(size_t)b * n + i];
  }
  as2[i] = s; ad2[i] = d;
}

// ---------- layer-2: per-dst denom + gamma scatter (16-lane group per dst) ----------
__global__ __launch_bounds__(256) void gamma_kernel(
    const int* __restrict__ off, const int* __restrict__ csr_src,
    const float* __restrict__ as2, const float* __restrict__ ad2,
    float* __restrict__ gamma, float invN, int n) {
  int d = (blockIdx.x * 256 + threadIdx.x) >> 4;
  int p = threadIdx.x & 15;
  if (d >= n) return;
  float adv = ad2[d];
  int beg = off[d], end = off[d + 1];
  float wsum = 0.f;
  for (int i = beg + p; i < end; i += 16) {
    float l = as2[csr_src[i]] + adv;
    l = l >= 0.f ? l : NEG_SLOPE * l;
    wsum += __expf(l);
  }
  wsum += __shfl_xor(wsum, 1, 16); wsum += __shfl_xor(wsum, 2, 16);
  wsum += __shfl_xor(wsum, 4, 16); wsum += __shfl_xor(wsum, 8, 16);
  float scale = invN / wsum;
  for (int i = beg + p; i < end; i += 16) {
    int s = csr_src[i];
    float l = as2[s] + adv;
    l = l >= 0.f ? l : NEG_SLOPE * l;
    atomicAdd(&gamma[s], __expf(l) * scale);
  }
}

// ---------- two-stage weighted column sum ----------
// stage 1: wave-per-row bf16x8 (one wave covers all 512 chans); LDS combine; per-block partial
__global__ __launch_bounds__(256) void colsum1_kernel(const __bf16* __restrict__ x1,
                                                      const float* __restrict__ gamma,
                                                      float* __restrict__ pcol, int n) {
  __shared__ float sc[512];
  int t = threadIdx.x;
  sc[t] = 0.f; sc[t + 256] = 0.f;
  __syncthreads();
  int lane = t & 63, w = t >> 6;
  float acc[8] = {};
  for (int r = blockIdx.x * 4 + w; r < n; r += gridDim.x * 4) {
    float g = gamma[r];
    bf16x8 v = *(const bf16x8*)(x1 + (size_t)r * 512 + lane * 8);
#pragma unroll
    for (int j = 0; j < 8; ++j) acc[j] += g * (float)v[j];
  }
#pragma unroll
  for (int j = 0; j < 8; ++j) atomicAdd(&sc[lane * 8 + j], acc[j]);
  __syncthreads();
  pcol[(size_t)blockIdx.x * 512 + t] = sc[t];
  pcol[(size_t)blockIdx.x * 512 + 256 + t] = sc[t + 256];
}

// stage 2: colsum[c] = sum_b pcol[b*512+c]
__global__ void colsum2_kernel(const float* __restrict__ pcol, float* __restrict__ colsum,
                               int nb) {
  int c = blockIdx.x * 256 + threadIdx.x;  // 512 total
  float a = 0.f;
  for (int b = 0; b < nb; ++b) a += pcol[(size_t)b * 512 + c];
  colsum[c] = a;
}

// ---------- final matvec: out[c] = colsum . W2[:,c] + b2[c] ----------
__global__ void final_kernel(const float* __restrict__ colsum, const float* __restrict__ W2,
                             const float* __restrict__ b2, float* __restrict__ out) {
  int c = threadIdx.x;  // 256
  int k0 = blockIdx.x * 64;  // 8 blocks x 64 k
  float acc = 0.f;
  for (int k = k0; k < k0 + 64; ++k) acc += colsum[k] * W2[(size_t)k * 256 + c];
  if (blockIdx.x == 0) acc += b2[c];
  atomicAdd(&out[c], acc);
}

__global__ void bcast_kernel(float* __restrict__ dout, int total) {
  int i = blockIdx.x * blockDim.x + threadIdx.x;
  if (i >= 256 && i < total) dout[i] = dout[i & 255];
}

// ---------- host ----------
extern "C" void kernel_launch(void* const* d_in, const int* in_sizes, int n_in,
                              void* d_out, int out_size, void* d_ws, size_t ws_size,
                              hipStream_t stream) {
  const int* ei = (const int*)d_in[0];
  const float* emb = (const float*)d_in[1];
  const float* W1 = (const float*)d_in[2];
  const float* as1w = (const float*)d_in[3];
  const float* ad1w = (const float*)d_in[4];
  const float* b1 = (const float*)d_in[5];
  const float* W2 = (const float*)d_in[6];
  const float* as2w = (const float*)d_in[7];
  const float* ad2w = (const float*)d_in[8];
  const float* b2 = (const float*)d_in[9];
  float* out = (float*)d_out;

  const int E = in_sizes[0] / 2;
  const int N = in_sizes[1] / 64;
  const int NT = E + N;
  const int CS1 = 2048;   // colsum stage-1 blocks

  char* ws = (char*)d_ws;
  size_t o = 0;
  auto alloc = [&](size_t bytes) { size_t r = o; o += (bytes + 255) & ~(size_t)255; return r; };
  __bf16* embb  = (__bf16*)(ws + alloc((size_t)N * 64 * 2));
  __bf16* aggE  = (__bf16*)(ws + alloc((size_t)N * 256 * 2));
  __bf16* x1    = (__bf16*)(ws + alloc((size_t)N * 512 * 2));
  __bf16* W1T   = (__bf16*)(ws + alloc((size_t)512 * 64 * 2));
  float* as1    = (float*)(ws + alloc((size_t)N * 4 * 4));
  float* ad1    = (float*)(ws + alloc((size_t)N * 4 * 4));
  float* as2    = (float*)(ws + alloc((size_t)N * 4));
  float* ad2    = (float*)(ws + alloc((size_t)N * 4));
  float* as2p   = (float*)(ws + alloc((size_t)8 * N * 4));
  float* ad2p   = (float*)(ws + alloc((size_t)8 * N * 4));
  float* pcol   = (float*)(ws + alloc((size_t)CS1 * 512 * 4));
  size_t zbeg = o;
  int* deg      = (int*)(ws + alloc((size_t)N * 4));
  int* cursor   = (int*)(ws + alloc((size_t)N * 4));
  float* gamma  = (float*)(ws + alloc((size_t)N * 4));
  size_t zend = o;
  float* colsum = (float*)(ws + alloc(512 * 4));
  int* off      = (int*)(ws + alloc((size_t)(N + 1) * 4));
  int* partial  = (int*)(ws + alloc(256 * 4));
  int* csr_src  = (int*)(ws + alloc((size_t)NT * 4));
  float* Vs1    = (float*)(ws + alloc(64 * 4 * 4));
  float* Vd1    = (float*)(ws + alloc(64 * 4 * 4));
  float* vs2    = (float*)(ws + alloc(512 * 4));
  float* vd2    = (float*)(ws + alloc(512 * 4));

  hipMemsetAsync(ws + zbeg, 0, zend - zbeg, stream);
  hipMemsetAsync(d_out, 0, (size_t)out_size * 4, stream);

  // merged independent prep (v1 | v2 | transpose | deg)
  int degBlocks = (E / 4 + 255) / 256;
  prep_all_kernel<<<131 + degBlocks, 256, 0, stream>>>(W1, as1w, ad1w, W2, as2w, ad2w, ei, E,
                                                       Vs1, Vd1, vs2, vd2, W1T, deg);
  int nb = (N + 255) / 256;
  emb_prep_kernel<<<nb, 256, 0, stream>>>(emb, Vs1, Vd1, embb, as1, ad1, N);

  // CSR: reduce -> final(inline prefix) -> scatter(+selfloop)
  scan_reduce_kernel<<<nb, 256, 0, stream>>>(deg, partial, N);
  scan_final_kernel<<<nb, 256, 0, stream>>>(deg, partial, off, N);
  int scatterBlocks = (E + 255) / 256;
  scatter_kernel<<<scatterBlocks + nb, 256, 0, stream>>>(ei, E, off, cursor, csr_src, N,
                                                         scatterBlocks);

  // layer 1
  agg_emb_kernel<<<N / 2, 128, 0, stream>>>(off, csr_src, embb, as1, ad1, aggE);
  dim3 g1((N + 127) / 128, 1, 4);
  gemm1p_kernel<<<g1, 256, 0, stream>>>(aggE, W1T, b1, vs2, vd2, x1, as2p, ad2p, N);
  merge_alpha2_kernel<<<nb, 256, 0, stream>>>(as2p, ad2p, as2, ad2, N);

  // layer 2 collapsed
  gamma_kernel<<<(N * 16 + 255) / 256, 256, 0, stream>>>(off, csr_src, as2, ad2, gamma,
                                                         1.0f / (float)N, N);
  colsum1_kernel<<<CS1, 256, 0, stream>>>(x1, gamma, pcol, N);
  colsum2_kernel<<<2, 256, 0, stream>>>(pcol, colsum, CS1);
  final_kernel<<<8, 256, 0, stream>>>(colsum, W2, b2, out);

  if (out_size > 256) {
    bcast_kernel<<<(out_size + 255) / 256, 256, 0, stream>>>(out, out_size);
  }
}

// Round 8
// 264.428 us; speedup vs baseline: 2.7644x; 2.7644x over previous
//
#include <hip/hip_runtime.h>
#include <cstdint>
#include <cstddef>

#define NEG_SLOPE 0.2f

typedef __bf16 bf16x8 __attribute__((ext_vector_type(8)));
typedef __bf16 bf16x4 __attribute__((ext_vector_type(4)));
typedef float f32x4 __attribute__((ext_vector_type(4)));

// ---------- merged independent prep: prep_v1 | prep_v2 | W1 transpose | deg ----------
// block ranges: [0] v1, [1,2] v2, [3,130] transpose, [131,131+degBlocks) deg
__global__ __launch_bounds__(256) void prep_all_kernel(
    const float* __restrict__ W1, const float* __restrict__ as1, const float* __restrict__ ad1,
    const float* __restrict__ W2, const float* __restrict__ as2, const float* __restrict__ ad2,
    const int* __restrict__ ei, int E,
    float* __restrict__ Vs, float* __restrict__ Vd,
    float* __restrict__ vs2, float* __restrict__ vd2,
    __bf16* __restrict__ W1T, int* __restrict__ deg) {
  int bid = blockIdx.x, tid = threadIdx.x;
  if (bid == 0) {
    int k = tid >> 2, h = tid & 3;
    const float* w = W1 + k * 512 + h * 128;
    const float* a1 = as1 + h * 128;
    const float* a2 = ad1 + h * 128;
    float s = 0.f, d = 0.f;
    for (int c = 0; c < 128; ++c) { float wv = w[c]; s += wv * a1[c]; d += wv * a2[c]; }
    Vs[k * 4 + h] = s; Vd[k * 4 + h] = d;
  } else if (bid <= 2) {
    int k = (bid - 1) * 256 + tid;
    if (k < 512) {
      const float* w = W2 + k * 256;
      float s = 0.f, d = 0.f;
      for (int c = 0; c < 256; ++c) { float wv = w[c]; s += wv * as2[c]; d += wv * ad2[c]; }
      vs2[k] = s; vd2[k] = d;
    }
  } else if (bid <= 130) {
    int idx = (bid - 3) * 256 + tid;   // < 32768
    int n = idx >> 6, k = idx & 63;    // W1T[n*64+k] = W1[k*512+n]
    W1T[idx] = (__bf16)W1[(size_t)k * 512 + n];
  } else {
    int t = (bid - 131) * 256 + tid;
    int base = t * 4;
    if (base >= E) return;
    if (base + 4 <= E) {
      int4 d4 = *(const int4*)(ei + E + base);
      atomicAdd(&deg[d4.x], 1);
      atomicAdd(&deg[d4.y], 1);
      atomicAdd(&deg[d4.z], 1);
      atomicAdd(&deg[d4.w], 1);
    } else {
      for (int e = base; e < E; ++e) atomicAdd(&deg[ei[E + e]], 1);
    }
  }
}

// ---------- fused emb -> bf16 + alpha1 ----------
__global__ void emb_prep_kernel(const float* __restrict__ emb, const float* __restrict__ Vs,
                                const float* __restrict__ Vd, __bf16* __restrict__ embb,
                                float* __restrict__ as_, float* __restrict__ ad_, int n) {
  __shared__ float sVs[256];
  __shared__ float sVd[256];
  for (int i = threadIdx.x; i < 256; i += blockDim.x) { sVs[i] = Vs[i]; sVd[i] = Vd[i]; }
  __syncthreads();
  int node = blockIdx.x * blockDim.x + threadIdx.x;
  if (node >= n) return;
  const float* xr = emb + (size_t)node * 64;
  __bf16* br = embb + (size_t)node * 64;
  float accs[4] = {}, accd[4] = {};
  for (int k = 0; k < 64; k += 4) {
    float4 xv = *(const float4*)(xr + k);
    bf16x4 o;
    o[0] = (__bf16)xv.x; o[1] = (__bf16)xv.y; o[2] = (__bf16)xv.z; o[3] = (__bf16)xv.w;
    *(bf16x4*)(br + k) = o;
#pragma unroll
    for (int h = 0; h < 4; ++h) {
      accs[h] += xv.x * sVs[(k + 0) * 4 + h] + xv.y * sVs[(k + 1) * 4 + h] +
                 xv.z * sVs[(k + 2) * 4 + h] + xv.w * sVs[(k + 3) * 4 + h];
      accd[h] += xv.x * sVd[(k + 0) * 4 + h] + xv.y * sVd[(k + 1) * 4 + h] +
                 xv.z * sVd[(k + 2) * 4 + h] + xv.w * sVd[(k + 3) * 4 + h];
    }
  }
#pragma unroll
  for (int h = 0; h < 4; ++h) {
    as_[(size_t)node * 4 + h] = accs[h];
    ad_[(size_t)node * 4 + h] = accd[h];
  }
}

// ---------- CSR scan ----------
__global__ void scan_reduce_kernel(const int* __restrict__ deg, int* __restrict__ partial, int n) {
  __shared__ int ws[4];
  int i = blockIdx.x * 256 + threadIdx.x;
  int v = (i < n) ? deg[i] + 1 : 0;
  int lane = threadIdx.x & 63, w = threadIdx.x >> 6;
#pragma unroll
  for (int s = 32; s; s >>= 1) v += __shfl_down(v, s, 64);
  if (lane == 0) ws[w] = v;
  __syncthreads();
  if (threadIdx.x == 0) partial[blockIdx.x] = ws[0] + ws[1] + ws[2] + ws[3];
}

// scan_final with inline prefix over partials
__global__ void scan_final_kernel(const int* __restrict__ deg, const int* __restrict__ partial,
                                  int* __restrict__ off, int n) {
  __shared__ int ws[4];
  __shared__ int bsum[4];
  __shared__ int sbase;
  int b = blockIdx.x, t = threadIdx.x;
  int lane = t & 63, w = t >> 6;
  int ps = (t < b) ? partial[t] : 0;    // b <= 255 assumed
#pragma unroll
  for (int s = 32; s; s >>= 1) ps += __shfl_down(ps, s, 64);
  if (lane == 0) bsum[w] = ps;
  __syncthreads();
  if (t == 0) sbase = bsum[0] + bsum[1] + bsum[2] + bsum[3];
  int i = b * 256 + t;
  int v = (i < n) ? deg[i] + 1 : 0;
  int x = v;
#pragma unroll
  for (int s = 1; s < 64; s <<= 1) {
    int tt = __shfl_up(x, s, 64);
    if (lane >= s) x += tt;
  }
  if (lane == 63) ws[w] = x;
  __syncthreads();
  int wo = 0;
  for (int k = 0; k < w; ++k) wo += ws[k];
  int base = sbase;
  if (i < n) off[i] = base + wo + x - v;
  if (i == n - 1) off[n] = base + wo + x;
}

// ---------- scatter real edges + self-loop tail slot ----------
__global__ void scatter_kernel(const int* __restrict__ ei, int E, const int* __restrict__ off,
                               int* __restrict__ cursor, int* __restrict__ csr_src, int n,
                               int scatterBlocks) {
  if ((int)blockIdx.x < scatterBlocks) {
    int e = blockIdx.x * 256 + threadIdx.x;
    if (e >= E) return;
    int s = ei[e], d = ei[E + e];
    int p = atomicAdd(&cursor[d], 1);
    csr_src[off[d] + p] = s;
  } else {
    int d = (blockIdx.x - scatterBlocks) * 256 + threadIdx.x;
    if (d < n) csr_src[off[d + 1] - 1] = d;
  }
}

// ---------- layer-1 aggregation in EMBEDDING space, 4 edges in flight ----------
__global__ __launch_bounds__(128) void agg_emb_kernel(
    const int* __restrict__ off, const int* __restrict__ csr_src,
    const __bf16* __restrict__ embb, const float* __restrict__ as_,
    const float* __restrict__ ad_, __bf16* __restrict__ aggE) {
  int d = blockIdx.x * 2 + (threadIdx.x >> 6);
  int lane = threadIdx.x & 63;
  int g = lane >> 4, p = lane & 15;
  float4 adv = *(const float4*)(ad_ + (size_t)d * 4);
  float acc[4][4] = {};   // [head][chan]
  float wsum[4] = {};
  int beg = off[d], end = off[d + 1];
  for (int i0 = beg; i0 < end; i0 += 4) {
    int i = i0 + g;
    float vm = (i < end) ? 1.f : 0.f;
    int idx = (i < end) ? i : (end - 1);
    int s = csr_src[idx];
    float4 asv = *(const float4*)(as_ + (size_t)s * 4);
    float l0 = asv.x + adv.x; l0 = l0 >= 0.f ? l0 : NEG_SLOPE * l0;
    float l1 = asv.y + adv.y; l1 = l1 >= 0.f ? l1 : NEG_SLOPE * l1;
    float l2 = asv.z + adv.z; l2 = l2 >= 0.f ? l2 : NEG_SLOPE * l2;
    float l3 = asv.w + adv.w; l3 = l3 >= 0.f ? l3 : NEG_SLOPE * l3;
    float w0 = __expf(l0) * vm, w1 = __expf(l1) * vm;
    float w2 = __expf(l2) * vm, w3 = __expf(l3) * vm;
    bf16x4 v = *(const bf16x4*)(embb + (size_t)s * 64 + p * 4);
    float f0 = (float)v[0], f1 = (float)v[1], f2 = (float)v[2], f3 = (float)v[3];
    acc[0][0] += w0 * f0; acc[0][1] += w0 * f1; acc[0][2] += w0 * f2; acc[0][3] += w0 * f3;
    acc[1][0] += w1 * f0; acc[1][1] += w1 * f1; acc[1][2] += w1 * f2; acc[1][3] += w1 * f3;
    acc[2][0] += w2 * f0; acc[2][1] += w2 * f1; acc[2][2] += w2 * f2; acc[2][3] += w2 * f3;
    acc[3][0] += w3 * f0; acc[3][1] += w3 * f1; acc[3][2] += w3 * f2; acc[3][3] += w3 * f3;
    wsum[0] += w0; wsum[1] += w1; wsum[2] += w2; wsum[3] += w3;
  }
#pragma unroll
  for (int h = 0; h < 4; ++h) {
#pragma unroll
    for (int c = 0; c < 4; ++c) {
      acc[h][c] += __shfl_xor(acc[h][c], 16, 64);
      acc[h][c] += __shfl_xor(acc[h][c], 32, 64);
    }
    wsum[h] += __shfl_xor(wsum[h], 16, 64);
    wsum[h] += __shfl_xor(wsum[h], 32, 64);
  }
  if (g == 0) {
#pragma unroll
    for (int h = 0; h < 4; ++h) {
      float inv = 1.0f / wsum[h];
      bf16x4 o;
      o[0] = (__bf16)(acc[h][0] * inv); o[1] = (__bf16)(acc[h][1] * inv);
      o[2] = (__bf16)(acc[h][2] * inv); o[3] = (__bf16)(acc[h][3] * inv);
      *(bf16x4*)(aggE + (size_t)d * 256 + h * 64 + p * 4) = o;
    }
  }
}

// ---------- reconstruct x1 (per-head MFMA GEMM + bias + ELU) with fused alpha2 partials ----------
__global__ __launch_bounds__(256) void gemm1p_kernel(const __bf16* __restrict__ aggE,
                                                     const __bf16* __restrict__ W1T,
                                                     const float* __restrict__ b1,
                                                     const float* __restrict__ vs2,
                                                     const float* __restrict__ vd2,
                                                     __bf16* __restrict__ x1,
                                                     float* __restrict__ as2p,
                                                     float* __restrict__ ad2p, int M) {
  __shared__ __bf16 Asl[128 * 72];
  __shared__ __bf16 Bsl[128 * 72];
  int tid = threadIdx.x;
  int h = blockIdx.z;
  int m0 = blockIdx.x * 128;
  int wave = tid >> 6, lane = tid & 63;
  int wm = (wave >> 1) * 64, wn = (wave & 1) * 64;
  int l15 = lane & 15, kg = lane >> 4;
#pragma unroll
  for (int i = 0; i < 4; ++i) {
    int c = tid + i * 256;
    int row = c >> 3, off = (c & 7) * 8;
    bf16x8 va = {};
    int gr = m0 + row;
    if (gr < M) va = *(const bf16x8*)(aggE + (size_t)gr * 256 + h * 64 + off);
    *(bf16x8*)(&Asl[row * 72 + off]) = va;
    bf16x8 vb = *(const bf16x8*)(W1T + ((size_t)h * 128 + row) * 64 + off);
    *(bf16x8*)(&Bsl[row * 72 + off]) = vb;
  }
  __syncthreads();
  f32x4 acc[4][4] = {};
#pragma unroll
  for (int ks = 0; ks < 2; ++ks) {
    bf16x8 af[4], bfr[4];
#pragma unroll
    for (int f = 0; f < 4; ++f) {
      af[f]  = *(const bf16x8*)(&Asl[(wm + f * 16 + l15) * 72 + kg * 8 + ks * 32]);
      bfr[f] = *(const bf16x8*)(&Bsl[(wn + f * 16 + l15) * 72 + kg * 8 + ks * 32]);
    }
#pragma unroll
    for (int i = 0; i < 4; ++i)
#pragma unroll
      for (int j = 0; j < 4; ++j)
        acc[i][j] = __builtin_amdgcn_mfma_f32_16x16x32_bf16(af[i], bfr[j], acc[i][j], 0, 0, 0);
  }
  float bv[4], vsv[4], vdv[4];
#pragma unroll
  for (int j = 0; j < 4; ++j) {
    int col = h * 128 + wn + j * 16 + l15;
    bv[j] = b1[col]; vsv[j] = vs2[col]; vdv[j] = vd2[col];
  }
  int slab = h * 2 + (wn >> 6);
#pragma unroll
  for (int i = 0; i < 4; ++i)
#pragma unroll
    for (int r = 0; r < 4; ++r) {
      int lrow = wm + i * 16 + kg * 4 + r;
      int row = m0 + lrow;
      bool vrow = row < M;
      float ps = 0.f, pd = 0.f;
#pragma unroll
      for (int j = 0; j < 4; ++j) {
        float a = acc[i][j][r] + bv[j];
        a = a > 0.f ? a : __expf(a) - 1.f;   // ELU
        __bf16 xb = (__bf16)a;
        if (vrow) x1[(size_t)row * 512 + h * 128 + wn + j * 16 + l15] = xb;
        float af = (float)xb;
        ps += af * vsv[j];
        pd += af * vdv[j];
      }
      ps += __shfl_xor(ps, 1, 16); ps += __shfl_xor(ps, 2, 16);
      ps += __shfl_xor(ps, 4, 16); ps += __shfl_xor(ps, 8, 16);
      pd += __shfl_xor(pd, 1, 16); pd += __shfl_xor(pd, 2, 16);
      pd += __shfl_xor(pd, 4, 16); pd += __shfl_xor(pd, 8, 16);
      if (l15 == 0 && vrow) {
        as2p[(size_t)slab * M + row] = ps;
        ad2p[(size_t)slab * M + row] = pd;
      }
    }
}

// ---------- merge alpha2 partial slabs ----------
__global__ void merge_alpha2_kernel(const float* __restrict__ as2p, const float* __restrict__ ad2p,
                                    float* __restrict__ as2, float* __restrict__ ad2, int n) {
  int i = blockIdx.x * blockDim.x + threadIdx.x;
  if (i >= n) return;
  float s = 0.f, d = 0.f;
#pragma unroll
  for (int b = 0; b < 8; ++b) {
    s += as2p[(size_t)b * n + i];
    d += ad2p[(size_t)b * n + i];
  }
  as2[i] = s; ad2[i] = d;
}

// ---------- layer-2: per-dst denom + gamma scatter (16-lane group per dst) ----------
__global__ __launch_bounds__(256) void gamma_kernel(
    const int* __restrict__ off, const int* __restrict__ csr_src,
    const float* __restrict__ as2, const float* __restrict__ ad2,
    float* __restrict__ gamma, float invN, int n) {
  int d = (blockIdx.x * 256 + threadIdx.x) >> 4;
  int p = threadIdx.x & 15;
  if (d >= n) return;
  float adv = ad2[d];
  int beg = off[d], end = off[d + 1];
  float wsum = 0.f;
  for (int i = beg + p; i < end; i += 16) {
    float l = as2[csr_src[i]] + adv;
    l = l >= 0.f ? l : NEG_SLOPE * l;
    wsum += __expf(l);
  }
  wsum += __shfl_xor(wsum, 1, 16); wsum += __shfl_xor(wsum, 2, 16);
  wsum += __shfl_xor(wsum, 4, 16); wsum += __shfl_xor(wsum, 8, 16);
  float scale = invN / wsum;
  for (int i = beg + p; i < end; i += 16) {
    int s = csr_src[i];
    float l = as2[s] + adv;
    l = l >= 0.f ? l : NEG_SLOPE * l;
    atomicAdd(&gamma[s], __expf(l) * scale);
  }
}

// ---------- two-stage weighted column sum ----------
// stage 1: wave-per-row bf16x8; LDS combine; per-block partial row (512 f32)
__global__ __launch_bounds__(256) void colsum1_kernel(const __bf16* __restrict__ x1,
                                                      const float* __restrict__ gamma,
                                                      float* __restrict__ pcol, int n) {
  __shared__ float sc[512];
  int t = threadIdx.x;
  sc[t] = 0.f; sc[t + 256] = 0.f;
  __syncthreads();
  int lane = t & 63, w = t >> 6;
  float acc[8] = {};
  for (int r = blockIdx.x * 4 + w; r < n; r += gridDim.x * 4) {
    float g = gamma[r];
    bf16x8 v = *(const bf16x8*)(x1 + (size_t)r * 512 + lane * 8);
#pragma unroll
    for (int j = 0; j < 8; ++j) acc[j] += g * (float)v[j];
  }
#pragma unroll
  for (int j = 0; j < 8; ++j) atomicAdd(&sc[lane * 8 + j], acc[j]);
  __syncthreads();
  pcol[(size_t)blockIdx.x * 512 + t] = sc[t];
  pcol[(size_t)blockIdx.x * 512 + 256 + t] = sc[t + 256];
}

// stage 2: parallel block-sliced reduction; block b sums rows [b*16, b*16+16)
// thread = 2 channels; atomicAdd into zeroed colsum
__global__ __launch_bounds__(256) void colsum2_kernel(const float* __restrict__ pcol,
                                                      float* __restrict__ colsum, int nb) {
  int c = threadIdx.x;
  int b0 = blockIdx.x * 16;
  float a0 = 0.f, a1 = 0.f;
#pragma unroll 4
  for (int b = b0; b < b0 + 16; ++b) {
    if (b < nb) {
      a0 += pcol[(size_t)b * 512 + c];
      a1 += pcol[(size_t)b * 512 + 256 + c];
    }
  }
  atomicAdd(&colsum[c], a0);
  atomicAdd(&colsum[c + 256], a1);
}

// ---------- final matvec: out[c] = colsum . W2[:,c] + b2[c] ----------
__global__ void final_kernel(const float* __restrict__ colsum, const float* __restrict__ W2,
                             const float* __restrict__ b2, float* __restrict__ out) {
  int c = threadIdx.x;  // 256
  int k0 = blockIdx.x * 64;  // 8 blocks x 64 k
  float acc = 0.f;
  for (int k = k0; k < k0 + 64; ++k) acc += colsum[k] * W2[(size_t)k * 256 + c];
  if (blockIdx.x == 0) acc += b2[c];
  atomicAdd(&out[c], acc);
}

__global__ void bcast_kernel(float* __restrict__ dout, int total) {
  int i = blockIdx.x * blockDim.x + threadIdx.x;
  if (i >= 256 && i < total) dout[i] = dout[i & 255];
}

// ---------- host ----------
extern "C" void kernel_launch(void* const* d_in, const int* in_sizes, int n_in,
                              void* d_out, int out_size, void* d_ws, size_t ws_size,
                              hipStream_t stream) {
  const int* ei = (const int*)d_in[0];
  const float* emb = (const float*)d_in[1];
  const float* W1 = (const float*)d_in[2];
  const float* as1w = (const float*)d_in[3];
  const float* ad1w = (const float*)d_in[4];
  const float* b1 = (const float*)d_in[5];
  const float* W2 = (const float*)d_in[6];
  const float* as2w = (const float*)d_in[7];
  const float* ad2w = (const float*)d_in[8];
  const float* b2 = (const float*)d_in[9];
  float* out = (float*)d_out;

  const int E = in_sizes[0] / 2;
  const int N = in_sizes[1] / 64;
  const int NT = E + N;
  const int CS1 = 1024;   // colsum stage-1 blocks

  char* ws = (char*)d_ws;
  size_t o = 0;
  auto alloc = [&](size_t bytes) { size_t r = o; o += (bytes + 255) & ~(size_t)255; return r; };
  __bf16* embb  = (__bf16*)(ws + alloc((size_t)N * 64 * 2));
  __bf16* aggE  = (__bf16*)(ws + alloc((size_t)N * 256 * 2));
  __bf16* x1    = (__bf16*)(ws + alloc((size_t)N * 512 * 2));
  __bf16* W1T   = (__bf16*)(ws + alloc((size_t)512 * 64 * 2));
  float* as1    = (float*)(ws + alloc((size_t)N * 4 * 4));
  float* ad1    = (float*)(ws + alloc((size_t)N * 4 * 4));
  float* as2    = (float*)(ws + alloc((size_t)N * 4));
  float* ad2    = (float*)(ws + alloc((size_t)N * 4));
  float* as2p   = (float*)(ws + alloc((size_t)8 * N * 4));
  float* ad2p   = (float*)(ws + alloc((size_t)8 * N * 4));
  float* pcol   = (float*)(ws + alloc((size_t)CS1 * 512 * 4));
  size_t zbeg = o;
  int* deg      = (int*)(ws + alloc((size_t)N * 4));
  int* cursor   = (int*)(ws + alloc((size_t)N * 4));
  float* gamma  = (float*)(ws + alloc((size_t)N * 4));
  float* colsum = (float*)(ws + alloc(512 * 4));
  size_t zend = o;
  int* off      = (int*)(ws + alloc((size_t)(N + 1) * 4));
  int* partial  = (int*)(ws + alloc(256 * 4));
  int* csr_src  = (int*)(ws + alloc((size_t)NT * 4));
  float* Vs1    = (float*)(ws + alloc(64 * 4 * 4));
  float* Vd1    = (float*)(ws + alloc(64 * 4 * 4));
  float* vs2    = (float*)(ws + alloc(512 * 4));
  float* vd2    = (float*)(ws + alloc(512 * 4));

  hipMemsetAsync(ws + zbeg, 0, zend - zbeg, stream);
  hipMemsetAsync(d_out, 0, (size_t)out_size * 4, stream);

  // merged independent prep (v1 | v2 | transpose | deg)
  int degBlocks = (E / 4 + 255) / 256;
  prep_all_kernel<<<131 + degBlocks, 256, 0, stream>>>(W1, as1w, ad1w, W2, as2w, ad2w, ei, E,
                                                       Vs1, Vd1, vs2, vd2, W1T, deg);
  int nb = (N + 255) / 256;
  emb_prep_kernel<<<nb, 256, 0, stream>>>(emb, Vs1, Vd1, embb, as1, ad1, N);

  // CSR: reduce -> final(inline prefix) -> scatter(+selfloop)
  scan_reduce_kernel<<<nb, 256, 0, stream>>>(deg, partial, N);
  scan_final_kernel<<<nb, 256, 0, stream>>>(deg, partial, off, N);
  int scatterBlocks = (E + 255) / 256;
  scatter_kernel<<<scatterBlocks + nb, 256, 0, stream>>>(ei, E, off, cursor, csr_src, N,
                                                         scatterBlocks);

  // layer 1
  agg_emb_kernel<<<N / 2, 128, 0, stream>>>(off, csr_src, embb, as1, ad1, aggE);
  dim3 g1((N + 127) / 128, 1, 4);
  gemm1p_kernel<<<g1, 256, 0, stream>>>(aggE, W1T, b1, vs2, vd2, x1, as2p, ad2p, N);
  merge_alpha2_kernel<<<nb, 256, 0, stream>>>(as2p, ad2p, as2, ad2, N);

  // layer 2 collapsed
  gamma_kernel<<<(N * 16 + 255) / 256, 256, 0, stream>>>(off, csr_src, as2, ad2, gamma,
                                                         1.0f / (float)N, N);
  colsum1_kernel<<<CS1, 256, 0, stream>>>(x1, gamma, pcol, N);
  colsum2_kernel<<<CS1 / 16, 256, 0, stream>>>(pcol, colsum, CS1);
  final_kernel<<<8, 256, 0, stream>>>(colsum, W2, b2, out);

  if (out_size > 256) {
    bcast_kernel<<<(out_size + 255) / 256, 256, 0, stream>>>(out, out_size);
  }
}